// Round 12
// baseline (644.221 us; speedup 1.0000x reference)
//
#include <hip/hip_runtime.h>
#include <hip/hip_bf16.h>
#include <hip/hip_fp16.h>

typedef __attribute__((ext_vector_type(8))) short bf16x8;
typedef __attribute__((ext_vector_type(4))) float f32x4;
typedef unsigned short ush;

static __device__ __forceinline__ void st(float* p, float v)  { *p = v; }
static __device__ __forceinline__ void st(__half* p, float v) { *p = __float2half(v); }

// fp32 -> bf16 RNE on raw bits
static __device__ __forceinline__ ush f2bf(float f) {
    unsigned int u = __builtin_bit_cast(unsigned int, f);
    unsigned int r = u + 0x7FFFu + ((u >> 16) & 1u);
    return (ush)(r >> 16);
}
static __device__ __forceinline__ float bf2f(ush h) {
    unsigned int u = ((unsigned int)h) << 16;
    return __builtin_bit_cast(float, u);
}
static __device__ __forceinline__ void split(float v, ush& hi, ush& lo) {
    hi = f2bf(v);
    lo = f2bf(v - bf2f(hi));
}

// vectorized f16 row loaders (CHUNK consecutive channels per lane)
static __device__ __forceinline__ void ldrow4(const __half* p, float* f) {
    const __half2* q = reinterpret_cast<const __half2*>(p);
    float2 a = __half22float2(q[0]), b = __half22float2(q[1]);
    f[0] = a.x; f[1] = a.y; f[2] = b.x; f[3] = b.y;
}
template <int CHUNK>
static __device__ __forceinline__ void ldrow(const __half* p, float* f) {
    if constexpr (CHUNK == 4) ldrow4(p, f); else f[0] = __half2float(*p);
}

// ---------------- CSR build ----------------
__global__ void k_init(int* deg, int N) {
    int i = blockIdx.x * blockDim.x + threadIdx.x;
    if (i < N) deg[i] = 1;              // self-loop
}

__global__ void k_hist(const int* __restrict__ ei, int* deg, int E) {
    int e = blockIdx.x * blockDim.x + threadIdx.x;
    if (e < E) atomicAdd(&deg[ei[E + e]], 1);
}

__global__ void k_scan1(const int* __restrict__ deg, int* __restrict__ offs,
                        int* __restrict__ bsum, int N) {
    __shared__ int sh[256];
    int i = blockIdx.x * 256 + threadIdx.x;
    int v = (i < N) ? deg[i] : 0;
    sh[threadIdx.x] = v;
    __syncthreads();
#pragma unroll
    for (int off = 1; off < 256; off <<= 1) {
        int t = (threadIdx.x >= off) ? sh[threadIdx.x - off] : 0;
        __syncthreads();
        sh[threadIdx.x] += t;
        __syncthreads();
    }
    if (i < N) offs[i] = sh[threadIdx.x] - v;
    if (threadIdx.x == 255) bsum[blockIdx.x] = sh[255];
}

__global__ void k_scan2(int* __restrict__ bsum, int nb) {   // nb <= 256, single block
    __shared__ int sh[256];
    int v = (threadIdx.x < nb) ? bsum[threadIdx.x] : 0;
    sh[threadIdx.x] = v;
    __syncthreads();
#pragma unroll
    for (int off = 1; off < 256; off <<= 1) {
        int t = (threadIdx.x >= off) ? sh[threadIdx.x - off] : 0;
        __syncthreads();
        sh[threadIdx.x] += t;
        __syncthreads();
    }
    if (threadIdx.x < nb) bsum[threadIdx.x] = sh[threadIdx.x] - v;
    if (threadIdx.x == 255) bsum[nb] = sh[255];
}

__global__ void k_scan3(int* __restrict__ offs, int* __restrict__ cursor,
                        const int* __restrict__ bsum, int N, int nb) {
    int i = blockIdx.x * 256 + threadIdx.x;
    if (i < N) {
        int v = offs[i] + bsum[blockIdx.x];
        offs[i] = v;
        cursor[i] = v;
    }
    if (i == 0) offs[N] = bsum[nb];
}

__global__ void k_scatter(const int* __restrict__ ei, int* cursor, int* csr, int E) {
    int e = blockIdx.x * blockDim.x + threadIdx.x;
    if (e < E) {
        int d = ei[E + e];
        int p = atomicAdd(&cursor[d], 1);
        csr[p] = ei[e];
    }
}

__global__ void k_scatter_loops(int* cursor, int* csr, int N) {
    int i = blockIdx.x * blockDim.x + threadIdx.x;
    if (i < N) { int p = atomicAdd(&cursor[i], 1); csr[p] = i; }
}

// ---------------- pre-split kernels ----------------
// W [K x M] fp32 -> transposed hi/lo bf16 [M x K]
__global__ void k_wsplit(const float* __restrict__ W, ush* __restrict__ Wth,
                         ush* __restrict__ Wtl, int K, int M) {
    int idx = blockIdx.x * 256 + threadIdx.x;
    if (idx < K * M) {
        int k = idx / M, n = idx - k * M;
        ush h, l;
        split(W[idx], h, l);
        Wth[(size_t)n * K + k] = h;
        Wtl[(size_t)n * K + k] = l;
    }
}

// x fp32 -> hi/lo bf16 (row-major, same layout)
__global__ void k_xsplit(const float* __restrict__ x, ush* __restrict__ xh,
                         ush* __restrict__ xl, long n) {
    long i = (long)blockIdx.x * 256 + threadIdx.x;
    if (i < n) {
        ush h, l;
        split(x[i], h, l);
        xh[i] = h;
        xl[i] = l;
    }
}

// ---------------- split-bf16 MFMA GEMM (pre-split inputs, pure-copy staging) ----------------
// C[nrows,M](f16) = (Ah+Al) @ (Wh+Wl): D += Ah*Bh + Ah*Bl + Al*Bh (lo*lo dropped).
// BM=128, BN=64, BK=32; 256 threads = 4 waves in 2x2; LDA=40 shorts (80B, 16B-aligned).
// LDS 30.7 KB -> 5 blocks/CU.
__global__ __launch_bounds__(256) void k_gemm_mfma(const ush* __restrict__ Ah, const ush* __restrict__ Al,
                                                   const ush* __restrict__ Wth, const ush* __restrict__ Wtl,
                                                   __half* __restrict__ C, int nrows, int K, int M) {
    constexpr int LDA = 40;
    __shared__ ush AH[128 * LDA];
    __shared__ ush AL[128 * LDA];
    __shared__ ush BH[64 * LDA];
    __shared__ ush BL[64 * LDA];

    int tid  = threadIdx.x;
    int lane = tid & 63;
    int wave = tid >> 6;
    int wr = wave & 1, wc = wave >> 1;
    int quad = lane >> 4, r = lane & 15;
    int r0 = blockIdx.x * 128, c0 = blockIdx.y * 64;

    f32x4 acc[4][2];
#pragma unroll
    for (int i = 0; i < 4; ++i)
#pragma unroll
        for (int j = 0; j < 2; ++j) acc[i][j] = (f32x4){0.f, 0.f, 0.f, 0.f};

    for (int kc = 0; kc < K; kc += 32) {
        // stage A: 128 rows x 32 k; 2 x 16B chunks per thread per matrix (pure copy)
#pragma unroll
        for (int it = 0; it < 2; ++it) {
            int row  = (tid >> 2) + it * 64;   // 0..127
            int kseg = (tid & 3) * 8;          // 0,8,16,24
            int gr = r0 + row;
            bf16x8 vh, vl;
            if (gr < nrows) {
                vh = *reinterpret_cast<const bf16x8*>(Ah + (size_t)gr * K + kc + kseg);
                vl = *reinterpret_cast<const bf16x8*>(Al + (size_t)gr * K + kc + kseg);
            } else {
                vh = (bf16x8){0,0,0,0,0,0,0,0};
                vl = (bf16x8){0,0,0,0,0,0,0,0};
            }
            *reinterpret_cast<bf16x8*>(&AH[row * LDA + kseg]) = vh;
            *reinterpret_cast<bf16x8*>(&AL[row * LDA + kseg]) = vl;
        }
        // stage B: 64 n x 32 k; 1 x 16B chunk per thread per matrix (pre-transposed: pure copy)
        {
            int n    = tid >> 2;               // 0..63
            int kseg = (tid & 3) * 8;
            bf16x8 vh = *reinterpret_cast<const bf16x8*>(Wth + (size_t)(c0 + n) * K + kc + kseg);
            bf16x8 vl = *reinterpret_cast<const bf16x8*>(Wtl + (size_t)(c0 + n) * K + kc + kseg);
            *reinterpret_cast<bf16x8*>(&BH[n * LDA + kseg]) = vh;
            *reinterpret_cast<bf16x8*>(&BL[n * LDA + kseg]) = vl;
        }
        __syncthreads();
        int k0 = quad * 8;
        bf16x8 ah[4], al[4], bh[2], bl[2];
#pragma unroll
        for (int tr = 0; tr < 4; ++tr) {
            int row = wr * 64 + tr * 16 + r;
            ah[tr] = *reinterpret_cast<const bf16x8*>(&AH[row * LDA + k0]);
            al[tr] = *reinterpret_cast<const bf16x8*>(&AL[row * LDA + k0]);
        }
#pragma unroll
        for (int tc = 0; tc < 2; ++tc) {
            int col = wc * 32 + tc * 16 + r;
            bh[tc] = *reinterpret_cast<const bf16x8*>(&BH[col * LDA + k0]);
            bl[tc] = *reinterpret_cast<const bf16x8*>(&BL[col * LDA + k0]);
        }
#pragma unroll
        for (int tr = 0; tr < 4; ++tr)
#pragma unroll
            for (int tc = 0; tc < 2; ++tc) {
                acc[tr][tc] = __builtin_amdgcn_mfma_f32_16x16x32_bf16(ah[tr], bh[tc], acc[tr][tc], 0, 0, 0);
                acc[tr][tc] = __builtin_amdgcn_mfma_f32_16x16x32_bf16(ah[tr], bl[tc], acc[tr][tc], 0, 0, 0);
                acc[tr][tc] = __builtin_amdgcn_mfma_f32_16x16x32_bf16(al[tr], bh[tc], acc[tr][tc], 0, 0, 0);
            }
        __syncthreads();
    }
    // epilogue: D lane mapping col=lane&15, row=quad*4+reg
#pragma unroll
    for (int tr = 0; tr < 4; ++tr)
#pragma unroll
        for (int tc = 0; tc < 2; ++tc) {
            int col = c0 + wc * 32 + tc * 16 + r;
#pragma unroll
            for (int i = 0; i < 4; ++i) {
                int row = r0 + wr * 64 + tr * 16 + quad * 4 + i;
                if (row < nrows) C[(size_t)row * M + col] = __float2half(acc[tr][tc][i]);
            }
        }
}

// ---------------- attention coefficients ----------------
template <int CHUNK>
__global__ void k_alpha(const __half* __restrict__ feat, const float* __restrict__ a_src,
                        const float* __restrict__ a_dst, float* __restrict__ als,
                        float* __restrict__ ald, int N) {
    constexpr int M = 64 * CHUNK;
    constexpr int H = M / 64;
    constexpr int WIDTH = 64 / H;
    int lane = threadIdx.x & 63;
    int node = blockIdx.x * 4 + (threadIdx.x >> 6);
    if (node >= N) return;
    float f[CHUNK];
    ldrow<CHUNK>(feat + (size_t)node * M + lane * CHUNK, f);
    float ps = 0.f, pd = 0.f;
#pragma unroll
    for (int j = 0; j < CHUNK; ++j) {
        int col = lane * CHUNK + j;
        ps += f[j] * a_src[col];
        pd += f[j] * a_dst[col];
    }
#pragma unroll
    for (int off = 1; off < WIDTH; off <<= 1) {
        ps += __shfl_xor(ps, off, 64);
        pd += __shfl_xor(pd, off, 64);
    }
    if ((lane & (WIDTH - 1)) == 0) {
        int head = lane / WIDTH;
        als[(size_t)node * H + head] = ps;
        ald[(size_t)node * H + head] = pd;
    }
}

// ---------------- GAT aggregation: 2-chain pipeline + fused softmax denominator.
// SPLIT=true: emit hi/lo bf16 (next GEMM's A operand). SPLIT=false: emit fp32.
template <int CHUNK, bool ELU, bool SPLIT>
__global__ void k_agg(const __half* __restrict__ feat, const int* __restrict__ offs,
                      const int* __restrict__ csr, const float* __restrict__ als,
                      const float* __restrict__ ald, const float* __restrict__ bias,
                      ush* __restrict__ outh, ush* __restrict__ outl,
                      float* __restrict__ outf, int N) {
    constexpr int M = 64 * CHUNK;
    constexpr int H = M / 64;
    int lane = threadIdx.x & 63;
    int node = blockIdx.x * 4 + (threadIdx.x >> 6);
    if (node >= N) return;
    int head = (CHUNK == 4) ? (lane >> 4) : 0;
    float ad = ald[(size_t)node * H + head];
    int beg = offs[node], end = offs[node + 1];
    const __half* fb = feat + (size_t)lane * CHUNK;

    float acc[CHUNK] = {};
    float den = 0.f;

    int   sA = csr[beg];
    int   sB = csr[(beg + 1 < end) ? beg + 1 : end - 1];
    float xA = als[(size_t)sA * H + head];
    float xB = als[(size_t)sB * H + head];
    float fA[CHUNK], fB[CHUNK];
    ldrow<CHUNK>(fb + (size_t)sA * M, fA);
    ldrow<CHUNK>(fb + (size_t)sB * M, fB);

    int e = beg;
    for (; e + 2 < end; e += 2) {
        int   sA2 = csr[e + 2];
        int   sB2 = csr[(e + 3 < end) ? e + 3 : end - 1];
        float xA2 = als[(size_t)sA2 * H + head];
        float xB2 = als[(size_t)sB2 * H + head];
        float fA2[CHUNK], fB2[CHUNK];
        ldrow<CHUNK>(fb + (size_t)sA2 * M, fA2);
        ldrow<CHUNK>(fb + (size_t)sB2 * M, fB2);
        float a = xA + ad; a = (a > 0.f) ? a : 0.2f * a;
        float wa = __expf(a);
        float b = xB + ad; b = (b > 0.f) ? b : 0.2f * b;
        float wb = __expf(b);
        den += wa + wb;
#pragma unroll
        for (int j = 0; j < CHUNK; ++j) {
            acc[j] = fmaf(wa, fA[j], acc[j]);
            acc[j] = fmaf(wb, fB[j], acc[j]);
        }
        xA = xA2; xB = xB2;
#pragma unroll
        for (int j = 0; j < CHUNK; ++j) { fA[j] = fA2[j]; fB[j] = fB2[j]; }
    }
    {
        float a = xA + ad; a = (a > 0.f) ? a : 0.2f * a;
        float wa = __expf(a);
        den += wa;
#pragma unroll
        for (int j = 0; j < CHUNK; ++j) acc[j] = fmaf(wa, fA[j], acc[j]);
        if (e + 1 < end) {
            float b = xB + ad; b = (b > 0.f) ? b : 0.2f * b;
            float wb = __expf(b);
            den += wb;
#pragma unroll
            for (int j = 0; j < CHUNK; ++j) acc[j] = fmaf(wb, fB[j], acc[j]);
        }
    }

    float inv = 1.f / (den + 1e-16f);
#pragma unroll
    for (int j = 0; j < CHUNK; ++j) {
        int col = lane * CHUNK + j;
        float v = acc[j] * inv + bias[col];
        if (ELU) v = (v > 0.f) ? v : (__expf(v) - 1.f);
        if (SPLIT) {
            ush h, l;
            split(v, h, l);
            outh[(size_t)node * M + col] = h;
            outl[(size_t)node * M + col] = l;
        } else {
            outf[(size_t)node * M + col] = v;
        }
    }
}

// ---------------- global mean pool: batch sorted -> one block per graph ----------------
static __device__ __forceinline__ int lowerb(const int* __restrict__ a, int n, int v) {
    int lo = 0, hi = n;
    while (lo < hi) { int mid = (lo + hi) >> 1; if (a[mid] < v) lo = mid + 1; else hi = mid; }
    return lo;
}

__global__ void k_pool2(const float* __restrict__ ne, const int* __restrict__ batch,
                        float* __restrict__ gout, int N) {
    int g = blockIdx.x;
    int lo = lowerb(batch, N, g);
    int hi = lowerb(batch, N, g + 1);
    int lane = threadIdx.x & 63, row = threadIdx.x >> 6;
    float s = 0.f;
    for (int i = lo + row; i < hi; i += 4) s += ne[(size_t)i * 64 + lane];
    __shared__ float red[4][64];
    red[row][lane] = s;
    __syncthreads();
    if (row == 0) {
        float v = red[0][lane] + red[1][lane] + red[2][lane] + red[3][lane];
        gout[(size_t)g * 64 + lane] = v / fmaxf((float)(hi - lo), 1.f);
    }
}

extern "C" void kernel_launch(void* const* d_in, const int* in_sizes, int n_in,
                              void* d_out, int out_size, void* d_ws, size_t ws_size,
                              hipStream_t stream) {
    const float* x   = (const float*)d_in[0];
    const int* ei    = (const int*)d_in[1];
    const int* batch = (const int*)d_in[2];
    const float* W1  = (const float*)d_in[3];
    const float* as1 = (const float*)d_in[4];
    const float* ad1 = (const float*)d_in[5];
    const float* b1  = (const float*)d_in[6];
    const float* W2  = (const float*)d_in[7];
    const float* as2 = (const float*)d_in[8];
    const float* ad2 = (const float*)d_in[9];
    const float* b2  = (const float*)d_in[10];
    const float* W3  = (const float*)d_in[11];
    const float* as3 = (const float*)d_in[12];
    const float* ad3 = (const float*)d_in[13];
    const float* b3  = (const float*)d_in[14];

    const int N = in_sizes[2];      // 50000
    const int E = in_sizes[1] / 2;  // 800000
    const int G = 64;
    float* out = (float*)d_out;

    // workspace (~87 MB)
    char* w = (char*)d_ws;
    auto carve = [&](size_t bytes) { char* p = w; w += (bytes + 255) & ~(size_t)255; return p; };
    __half* feat = (__half*)carve((size_t)N * 256 * 2);   // GEMM output (f16)
    ush* ah      = (ush*)carve((size_t)N * 256 * 2);      // A operand hi (bf16)
    ush* al      = (ush*)carve((size_t)N * 256 * 2);      // A operand lo
    float* als   = (float*)carve((size_t)N * 4 * 4);
    float* ald   = (float*)carve((size_t)N * 4 * 4);
    int* deg     = (int*)carve((size_t)N * 4);
    int* offs    = (int*)carve((size_t)(N + 1) * 4);
    int* cursor  = (int*)carve((size_t)N * 4);
    int* csr     = (int*)carve((size_t)(E + N) * 4);
    int nb       = (N + 255) / 256;
    int* bsum    = (int*)carve((size_t)(nb + 1) * 4);
    ush* w1h     = (ush*)carve((size_t)256 * 256 * 2);
    ush* w1l     = (ush*)carve((size_t)256 * 256 * 2);
    ush* w2h     = (ush*)carve((size_t)256 * 256 * 2);
    ush* w2l     = (ush*)carve((size_t)256 * 256 * 2);
    ush* w3h     = (ush*)carve((size_t)256 * 64 * 2);
    ush* w3l     = (ush*)carve((size_t)256 * 64 * 2);

    // CSR build
    k_init<<<(N + 255) / 256, 256, 0, stream>>>(deg, N);
    k_hist<<<(E + 255) / 256, 256, 0, stream>>>(ei, deg, E);
    k_scan1<<<nb, 256, 0, stream>>>(deg, offs, bsum, N);
    k_scan2<<<1, 256, 0, stream>>>(bsum, nb);
    k_scan3<<<nb, 256, 0, stream>>>(offs, cursor, bsum, N, nb);
    k_scatter<<<(E + 255) / 256, 256, 0, stream>>>(ei, cursor, csr, E);
    k_scatter_loops<<<(N + 255) / 256, 256, 0, stream>>>(cursor, csr, N);

    // pre-split weights (transposed) and layer-1 input
    k_wsplit<<<(256 * 256 + 255) / 256, 256, 0, stream>>>(W1, w1h, w1l, 256, 256);
    k_wsplit<<<(256 * 256 + 255) / 256, 256, 0, stream>>>(W2, w2h, w2l, 256, 256);
    k_wsplit<<<(256 * 64 + 255) / 256, 256, 0, stream>>>(W3, w3h, w3l, 256, 64);
    long nx = (long)N * 256;
    k_xsplit<<<(int)((nx + 255) / 256), 256, 0, stream>>>(x, ah, al, nx);

    dim3 gemmBig((N + 127) / 128, 4);
    dim3 gemmSmall((N + 127) / 128, 1);
    int nodeBlocks = (N + 3) / 4;

    // layer 1
    k_gemm_mfma<<<gemmBig, 256, 0, stream>>>(ah, al, w1h, w1l, feat, N, 256, 256);
    k_alpha<4><<<nodeBlocks, 256, 0, stream>>>(feat, as1, ad1, als, ald, N);
    k_agg<4, true, true><<<nodeBlocks, 256, 0, stream>>>(feat, offs, csr, als, ald, b1, ah, al, nullptr, N);
    // layer 2
    k_gemm_mfma<<<gemmBig, 256, 0, stream>>>(ah, al, w2h, w2l, feat, N, 256, 256);
    k_alpha<4><<<nodeBlocks, 256, 0, stream>>>(feat, as2, ad2, als, ald, N);
    k_agg<4, true, true><<<nodeBlocks, 256, 0, stream>>>(feat, offs, csr, als, ald, b2, ah, al, nullptr, N);
    // layer 3: 256 -> 64, single head, no ELU; fp32 straight to d_out
    k_gemm_mfma<<<gemmSmall, 256, 0, stream>>>(ah, al, w3h, w3l, feat, N, 256, 64);
    k_alpha<1><<<nodeBlocks, 256, 0, stream>>>(feat, as3, ad3, als, ald, N);
    k_agg<1, false, false><<<nodeBlocks, 256, 0, stream>>>(feat, offs, csr, als, ald, b3, nullptr, nullptr, out, N);

    // global mean pool
    k_pool2<<<G, 256, 0, stream>>>(out, batch, out + (size_t)N * 64, N);
}

// Round 13
// 609.787 us; speedup vs baseline: 1.0565x; 1.0565x over previous
//
#include <hip/hip_runtime.h>
#include <hip/hip_bf16.h>
#include <hip/hip_fp16.h>

typedef __attribute__((ext_vector_type(8))) _Float16 f16x8;
typedef __attribute__((ext_vector_type(4))) float f32x4;

static __device__ __forceinline__ void st(float* p, float v)  { *p = v; }
static __device__ __forceinline__ void st(__half* p, float v) { *p = __float2half(v); }

// fp32 -> f16 hi/lo split (residual <= 2^-22 relative)
static __device__ __forceinline__ void splitf16(float v, __half& hi, __half& lo) {
    hi = __float2half(v);
    lo = __float2half(v - __half2float(hi));
}

// vectorized f16 row loaders (CHUNK consecutive channels per lane)
static __device__ __forceinline__ void ldrow4(const __half* p, float* f) {
    const __half2* q = reinterpret_cast<const __half2*>(p);
    float2 a = __half22float2(q[0]), b = __half22float2(q[1]);
    f[0] = a.x; f[1] = a.y; f[2] = b.x; f[3] = b.y;
}
template <int CHUNK>
static __device__ __forceinline__ void ldrow(const __half* p, float* f) {
    if constexpr (CHUNK == 4) ldrow4(p, f); else f[0] = __half2float(*p);
}

// ---------------- CSR build ----------------
__global__ void k_init(int* deg, int N) {
    int i = blockIdx.x * blockDim.x + threadIdx.x;
    if (i < N) deg[i] = 1;              // self-loop
}

__global__ void k_hist(const int* __restrict__ ei, int* deg, int E) {
    int e = blockIdx.x * blockDim.x + threadIdx.x;
    if (e < E) atomicAdd(&deg[ei[E + e]], 1);
}

__global__ void k_scan1(const int* __restrict__ deg, int* __restrict__ offs,
                        int* __restrict__ bsum, int N) {
    __shared__ int sh[256];
    int i = blockIdx.x * 256 + threadIdx.x;
    int v = (i < N) ? deg[i] : 0;
    sh[threadIdx.x] = v;
    __syncthreads();
#pragma unroll
    for (int off = 1; off < 256; off <<= 1) {
        int t = (threadIdx.x >= off) ? sh[threadIdx.x - off] : 0;
        __syncthreads();
        sh[threadIdx.x] += t;
        __syncthreads();
    }
    if (i < N) offs[i] = sh[threadIdx.x] - v;
    if (threadIdx.x == 255) bsum[blockIdx.x] = sh[255];
}

__global__ void k_scan2(int* __restrict__ bsum, int nb) {   // nb <= 256, single block
    __shared__ int sh[256];
    int v = (threadIdx.x < nb) ? bsum[threadIdx.x] : 0;
    sh[threadIdx.x] = v;
    __syncthreads();
#pragma unroll
    for (int off = 1; off < 256; off <<= 1) {
        int t = (threadIdx.x >= off) ? sh[threadIdx.x - off] : 0;
        __syncthreads();
        sh[threadIdx.x] += t;
        __syncthreads();
    }
    if (threadIdx.x < nb) bsum[threadIdx.x] = sh[threadIdx.x] - v;
    if (threadIdx.x == 255) bsum[nb] = sh[255];
}

__global__ void k_scan3(int* __restrict__ offs, int* __restrict__ cursor,
                        const int* __restrict__ bsum, int N, int nb) {
    int i = blockIdx.x * 256 + threadIdx.x;
    if (i < N) {
        int v = offs[i] + bsum[blockIdx.x];
        offs[i] = v;
        cursor[i] = v;
    }
    if (i == 0) offs[N] = bsum[nb];
}

__global__ void k_scatter(const int* __restrict__ ei, int* cursor, int* csr, int E) {
    int e = blockIdx.x * blockDim.x + threadIdx.x;
    if (e < E) {
        int d = ei[E + e];
        int p = atomicAdd(&cursor[d], 1);
        csr[p] = ei[e];
    }
}

__global__ void k_scatter_loops(int* cursor, int* csr, int N) {
    int i = blockIdx.x * blockDim.x + threadIdx.x;
    if (i < N) { int p = atomicAdd(&cursor[i], 1); csr[p] = i; }
}

// ---------------- pre-split kernels (f16 basis) ----------------
// W [K x M] fp32 -> transposed f16 hi/lo [M x K]
__global__ void k_wsplit(const float* __restrict__ W, __half* __restrict__ Wth,
                         __half* __restrict__ Wtl, int K, int M) {
    int idx = blockIdx.x * 256 + threadIdx.x;
    if (idx < K * M) {
        int k = idx / M, n = idx - k * M;
        __half h, l;
        splitf16(W[idx], h, l);
        Wth[(size_t)n * K + k] = h;
        Wtl[(size_t)n * K + k] = l;
    }
}

// x fp32 -> f16 hi/lo (row-major)
__global__ void k_xsplit(const float* __restrict__ x, __half* __restrict__ xh,
                         __half* __restrict__ xl, long n) {
    long i = (long)blockIdx.x * 256 + threadIdx.x;
    if (i < n) {
        __half h, l;
        splitf16(x[i], h, l);
        xh[i] = h;
        xl[i] = l;
    }
}

// ---------------- f16-split MFMA GEMMs ----------------
// Layer 1 (3-term): C = (Ah+Al) @ (Wh+Wl) ~= AhWh + AhWl + AlWh
// BM=128, BN=64, BK=32; 4 waves 2x2; LDA=40 halves (80B, 16B-aligned).
__global__ __launch_bounds__(256) void k_gemm3(const __half* __restrict__ Ah, const __half* __restrict__ Al,
                                               const __half* __restrict__ Wth, const __half* __restrict__ Wtl,
                                               __half* __restrict__ C, int nrows, int K, int M) {
    constexpr int LDA = 40;
    __shared__ __half AH[128 * LDA];
    __shared__ __half AL[128 * LDA];
    __shared__ __half BH[64 * LDA];
    __shared__ __half BL[64 * LDA];

    int tid  = threadIdx.x;
    int lane = tid & 63;
    int wave = tid >> 6;
    int wr = wave & 1, wc = wave >> 1;
    int quad = lane >> 4, r = lane & 15;
    int r0 = blockIdx.x * 128, c0 = blockIdx.y * 64;

    f32x4 acc[4][2];
#pragma unroll
    for (int i = 0; i < 4; ++i)
#pragma unroll
        for (int j = 0; j < 2; ++j) acc[i][j] = (f32x4){0.f, 0.f, 0.f, 0.f};

    for (int kc = 0; kc < K; kc += 32) {
#pragma unroll
        for (int it = 0; it < 2; ++it) {
            int row  = (tid >> 2) + it * 64;
            int kseg = (tid & 3) * 8;
            int gr = r0 + row;
            f16x8 vh = (f16x8)(_Float16)0, vl = (f16x8)(_Float16)0;
            if (gr < nrows) {
                vh = *reinterpret_cast<const f16x8*>(Ah + (size_t)gr * K + kc + kseg);
                vl = *reinterpret_cast<const f16x8*>(Al + (size_t)gr * K + kc + kseg);
            }
            *reinterpret_cast<f16x8*>(&AH[row * LDA + kseg]) = vh;
            *reinterpret_cast<f16x8*>(&AL[row * LDA + kseg]) = vl;
        }
        {
            int n    = tid >> 2;
            int kseg = (tid & 3) * 8;
            *reinterpret_cast<f16x8*>(&BH[n * LDA + kseg]) =
                *reinterpret_cast<const f16x8*>(Wth + (size_t)(c0 + n) * K + kc + kseg);
            *reinterpret_cast<f16x8*>(&BL[n * LDA + kseg]) =
                *reinterpret_cast<const f16x8*>(Wtl + (size_t)(c0 + n) * K + kc + kseg);
        }
        __syncthreads();
        int k0 = quad * 8;
        f16x8 ah[4], al[4], bh[2], bl[2];
#pragma unroll
        for (int tr = 0; tr < 4; ++tr) {
            int row = wr * 64 + tr * 16 + r;
            ah[tr] = *reinterpret_cast<const f16x8*>(&AH[row * LDA + k0]);
            al[tr] = *reinterpret_cast<const f16x8*>(&AL[row * LDA + k0]);
        }
#pragma unroll
        for (int tc = 0; tc < 2; ++tc) {
            int col = wc * 32 + tc * 16 + r;
            bh[tc] = *reinterpret_cast<const f16x8*>(&BH[col * LDA + k0]);
            bl[tc] = *reinterpret_cast<const f16x8*>(&BL[col * LDA + k0]);
        }
#pragma unroll
        for (int tr = 0; tr < 4; ++tr)
#pragma unroll
            for (int tc = 0; tc < 2; ++tc) {
                acc[tr][tc] = __builtin_amdgcn_mfma_f32_16x16x32_f16(ah[tr], bh[tc], acc[tr][tc], 0, 0, 0);
                acc[tr][tc] = __builtin_amdgcn_mfma_f32_16x16x32_f16(ah[tr], bl[tc], acc[tr][tc], 0, 0, 0);
                acc[tr][tc] = __builtin_amdgcn_mfma_f32_16x16x32_f16(al[tr], bh[tc], acc[tr][tc], 0, 0, 0);
            }
        __syncthreads();
    }
#pragma unroll
    for (int tr = 0; tr < 4; ++tr)
#pragma unroll
        for (int tc = 0; tc < 2; ++tc) {
            int col = c0 + wc * 32 + tc * 16 + r;
#pragma unroll
            for (int i = 0; i < 4; ++i) {
                int row = r0 + wr * 64 + tr * 16 + quad * 4 + i;
                if (row < nrows) C[(size_t)row * M + col] = __float2half(acc[tr][tc][i]);
            }
        }
}

// Layers 2/3 (2-term): A is exact f16 -> C = A @ (Wh+Wl). LDS ~20.5 KB.
__global__ __launch_bounds__(256) void k_gemm2(const __half* __restrict__ A,
                                               const __half* __restrict__ Wth, const __half* __restrict__ Wtl,
                                               __half* __restrict__ C, int nrows, int K, int M) {
    constexpr int LDA = 40;
    __shared__ __half AS[128 * LDA];
    __shared__ __half BH[64 * LDA];
    __shared__ __half BL[64 * LDA];

    int tid  = threadIdx.x;
    int lane = tid & 63;
    int wave = tid >> 6;
    int wr = wave & 1, wc = wave >> 1;
    int quad = lane >> 4, r = lane & 15;
    int r0 = blockIdx.x * 128, c0 = blockIdx.y * 64;

    f32x4 acc[4][2];
#pragma unroll
    for (int i = 0; i < 4; ++i)
#pragma unroll
        for (int j = 0; j < 2; ++j) acc[i][j] = (f32x4){0.f, 0.f, 0.f, 0.f};

    for (int kc = 0; kc < K; kc += 32) {
#pragma unroll
        for (int it = 0; it < 2; ++it) {
            int row  = (tid >> 2) + it * 64;
            int kseg = (tid & 3) * 8;
            int gr = r0 + row;
            f16x8 v = (f16x8)(_Float16)0;
            if (gr < nrows) v = *reinterpret_cast<const f16x8*>(A + (size_t)gr * K + kc + kseg);
            *reinterpret_cast<f16x8*>(&AS[row * LDA + kseg]) = v;
        }
        {
            int n    = tid >> 2;
            int kseg = (tid & 3) * 8;
            *reinterpret_cast<f16x8*>(&BH[n * LDA + kseg]) =
                *reinterpret_cast<const f16x8*>(Wth + (size_t)(c0 + n) * K + kc + kseg);
            *reinterpret_cast<f16x8*>(&BL[n * LDA + kseg]) =
                *reinterpret_cast<const f16x8*>(Wtl + (size_t)(c0 + n) * K + kc + kseg);
        }
        __syncthreads();
        int k0 = quad * 8;
        f16x8 a[4], bh[2], bl[2];
#pragma unroll
        for (int tr = 0; tr < 4; ++tr) {
            int row = wr * 64 + tr * 16 + r;
            a[tr] = *reinterpret_cast<const f16x8*>(&AS[row * LDA + k0]);
        }
#pragma unroll
        for (int tc = 0; tc < 2; ++tc) {
            int col = wc * 32 + tc * 16 + r;
            bh[tc] = *reinterpret_cast<const f16x8*>(&BH[col * LDA + k0]);
            bl[tc] = *reinterpret_cast<const f16x8*>(&BL[col * LDA + k0]);
        }
#pragma unroll
        for (int tr = 0; tr < 4; ++tr)
#pragma unroll
            for (int tc = 0; tc < 2; ++tc) {
                acc[tr][tc] = __builtin_amdgcn_mfma_f32_16x16x32_f16(a[tr], bh[tc], acc[tr][tc], 0, 0, 0);
                acc[tr][tc] = __builtin_amdgcn_mfma_f32_16x16x32_f16(a[tr], bl[tc], acc[tr][tc], 0, 0, 0);
            }
        __syncthreads();
    }
#pragma unroll
    for (int tr = 0; tr < 4; ++tr)
#pragma unroll
        for (int tc = 0; tc < 2; ++tc) {
            int col = c0 + wc * 32 + tc * 16 + r;
#pragma unroll
            for (int i = 0; i < 4; ++i) {
                int row = r0 + wr * 64 + tr * 16 + quad * 4 + i;
                if (row < nrows) C[(size_t)row * M + col] = __float2half(acc[tr][tc][i]);
            }
        }
}

// ---------------- attention coefficients ----------------
template <int CHUNK>
__global__ void k_alpha(const __half* __restrict__ feat, const float* __restrict__ a_src,
                        const float* __restrict__ a_dst, float* __restrict__ als,
                        float* __restrict__ ald, int N) {
    constexpr int M = 64 * CHUNK;
    constexpr int H = M / 64;
    constexpr int WIDTH = 64 / H;
    int lane = threadIdx.x & 63;
    int node = blockIdx.x * 4 + (threadIdx.x >> 6);
    if (node >= N) return;
    float f[CHUNK];
    ldrow<CHUNK>(feat + (size_t)node * M + lane * CHUNK, f);
    float ps = 0.f, pd = 0.f;
#pragma unroll
    for (int j = 0; j < CHUNK; ++j) {
        int col = lane * CHUNK + j;
        ps += f[j] * a_src[col];
        pd += f[j] * a_dst[col];
    }
#pragma unroll
    for (int off = 1; off < WIDTH; off <<= 1) {
        ps += __shfl_xor(ps, off, 64);
        pd += __shfl_xor(pd, off, 64);
    }
    if ((lane & (WIDTH - 1)) == 0) {
        int head = lane / WIDTH;
        als[(size_t)node * H + head] = ps;
        ald[(size_t)node * H + head] = pd;
    }
}

// ---------------- GAT aggregation: 2-chain pipeline + fused softmax denominator ----------------
template <int CHUNK, bool ELU, typename OT>
__global__ void k_agg(const __half* __restrict__ feat, const int* __restrict__ offs,
                      const int* __restrict__ csr, const float* __restrict__ als,
                      const float* __restrict__ ald, const float* __restrict__ bias,
                      OT* __restrict__ out, int N) {
    constexpr int M = 64 * CHUNK;
    constexpr int H = M / 64;
    int lane = threadIdx.x & 63;
    int node = blockIdx.x * 4 + (threadIdx.x >> 6);
    if (node >= N) return;
    int head = (CHUNK == 4) ? (lane >> 4) : 0;
    float ad = ald[(size_t)node * H + head];
    int beg = offs[node], end = offs[node + 1];
    const __half* fb = feat + (size_t)lane * CHUNK;

    float acc[CHUNK] = {};
    float den = 0.f;

    int   sA = csr[beg];
    int   sB = csr[(beg + 1 < end) ? beg + 1 : end - 1];
    float xA = als[(size_t)sA * H + head];
    float xB = als[(size_t)sB * H + head];
    float fA[CHUNK], fB[CHUNK];
    ldrow<CHUNK>(fb + (size_t)sA * M, fA);
    ldrow<CHUNK>(fb + (size_t)sB * M, fB);

    int e = beg;
    for (; e + 2 < end; e += 2) {
        int   sA2 = csr[e + 2];
        int   sB2 = csr[(e + 3 < end) ? e + 3 : end - 1];
        float xA2 = als[(size_t)sA2 * H + head];
        float xB2 = als[(size_t)sB2 * H + head];
        float fA2[CHUNK], fB2[CHUNK];
        ldrow<CHUNK>(fb + (size_t)sA2 * M, fA2);
        ldrow<CHUNK>(fb + (size_t)sB2 * M, fB2);
        float a = xA + ad; a = (a > 0.f) ? a : 0.2f * a;
        float wa = __expf(a);
        float b = xB + ad; b = (b > 0.f) ? b : 0.2f * b;
        float wb = __expf(b);
        den += wa + wb;
#pragma unroll
        for (int j = 0; j < CHUNK; ++j) {
            acc[j] = fmaf(wa, fA[j], acc[j]);
            acc[j] = fmaf(wb, fB[j], acc[j]);
        }
        xA = xA2; xB = xB2;
#pragma unroll
        for (int j = 0; j < CHUNK; ++j) { fA[j] = fA2[j]; fB[j] = fB2[j]; }
    }
    {
        float a = xA + ad; a = (a > 0.f) ? a : 0.2f * a;
        float wa = __expf(a);
        den += wa;
#pragma unroll
        for (int j = 0; j < CHUNK; ++j) acc[j] = fmaf(wa, fA[j], acc[j]);
        if (e + 1 < end) {
            float b = xB + ad; b = (b > 0.f) ? b : 0.2f * b;
            float wb = __expf(b);
            den += wb;
#pragma unroll
            for (int j = 0; j < CHUNK; ++j) acc[j] = fmaf(wb, fB[j], acc[j]);
        }
    }

    float inv = 1.f / (den + 1e-16f);
#pragma unroll
    for (int j = 0; j < CHUNK; ++j) {
        int col = lane * CHUNK + j;
        float v = acc[j] * inv + bias[col];
        if (ELU) v = (v > 0.f) ? v : (__expf(v) - 1.f);
        st(&out[(size_t)node * M + col], v);
    }
}

// ---------------- global mean pool: batch sorted -> one block per graph ----------------
static __device__ __forceinline__ int lowerb(const int* __restrict__ a, int n, int v) {
    int lo = 0, hi = n;
    while (lo < hi) { int mid = (lo + hi) >> 1; if (a[mid] < v) lo = mid + 1; else hi = mid; }
    return lo;
}

__global__ void k_pool2(const float* __restrict__ ne, const int* __restrict__ batch,
                        float* __restrict__ gout, int N) {
    int g = blockIdx.x;
    int lo = lowerb(batch, N, g);
    int hi = lowerb(batch, N, g + 1);
    int lane = threadIdx.x & 63, row = threadIdx.x >> 6;
    float s = 0.f;
    for (int i = lo + row; i < hi; i += 4) s += ne[(size_t)i * 64 + lane];
    __shared__ float red[4][64];
    red[row][lane] = s;
    __syncthreads();
    if (row == 0) {
        float v = red[0][lane] + red[1][lane] + red[2][lane] + red[3][lane];
        gout[(size_t)g * 64 + lane] = v / fmaxf((float)(hi - lo), 1.f);
    }
}

extern "C" void kernel_launch(void* const* d_in, const int* in_sizes, int n_in,
                              void* d_out, int out_size, void* d_ws, size_t ws_size,
                              hipStream_t stream) {
    const float* x   = (const float*)d_in[0];
    const int* ei    = (const int*)d_in[1];
    const int* batch = (const int*)d_in[2];
    const float* W1  = (const float*)d_in[3];
    const float* as1 = (const float*)d_in[4];
    const float* ad1 = (const float*)d_in[5];
    const float* b1  = (const float*)d_in[6];
    const float* W2  = (const float*)d_in[7];
    const float* as2 = (const float*)d_in[8];
    const float* ad2 = (const float*)d_in[9];
    const float* b2  = (const float*)d_in[10];
    const float* W3  = (const float*)d_in[11];
    const float* as3 = (const float*)d_in[12];
    const float* ad3 = (const float*)d_in[13];
    const float* b3  = (const float*)d_in[14];

    const int N = in_sizes[2];      // 50000
    const int E = in_sizes[1] / 2;  // 800000
    const int G = 64;
    float* out = (float*)d_out;

    // workspace (~85 MB). act aliases xh (xh/xl dead after layer-1 GEMM).
    char* w = (char*)d_ws;
    auto carve = [&](size_t bytes) { char* p = w; w += (bytes + 255) & ~(size_t)255; return p; };
    __half* feat = (__half*)carve((size_t)N * 256 * 2);   // GEMM output (f16)
    __half* xh   = (__half*)carve((size_t)N * 256 * 2);   // layer-1 A hi; later act
    __half* xl   = (__half*)carve((size_t)N * 256 * 2);   // layer-1 A lo
    __half* act  = xh;                                     // alias: safe after gemm3
    float* als   = (float*)carve((size_t)N * 4 * 4);
    float* ald   = (float*)carve((size_t)N * 4 * 4);
    int* deg     = (int*)carve((size_t)N * 4);
    int* offs    = (int*)carve((size_t)(N + 1) * 4);
    int* cursor  = (int*)carve((size_t)N * 4);
    int* csr     = (int*)carve((size_t)(E + N) * 4);
    int nb       = (N + 255) / 256;
    int* bsum    = (int*)carve((size_t)(nb + 1) * 4);
    __half* w1h  = (__half*)carve((size_t)256 * 256 * 2);
    __half* w1l  = (__half*)carve((size_t)256 * 256 * 2);
    __half* w2h  = (__half*)carve((size_t)256 * 256 * 2);
    __half* w2l  = (__half*)carve((size_t)256 * 256 * 2);
    __half* w3h  = (__half*)carve((size_t)256 * 64 * 2);
    __half* w3l  = (__half*)carve((size_t)256 * 64 * 2);

    // CSR build
    k_init<<<(N + 255) / 256, 256, 0, stream>>>(deg, N);
    k_hist<<<(E + 255) / 256, 256, 0, stream>>>(ei, deg, E);
    k_scan1<<<nb, 256, 0, stream>>>(deg, offs, bsum, N);
    k_scan2<<<1, 256, 0, stream>>>(bsum, nb);
    k_scan3<<<nb, 256, 0, stream>>>(offs, cursor, bsum, N, nb);
    k_scatter<<<(E + 255) / 256, 256, 0, stream>>>(ei, cursor, csr, E);
    k_scatter_loops<<<(N + 255) / 256, 256, 0, stream>>>(cursor, csr, N);

    // pre-split weights (transposed, f16 hi/lo) and layer-1 input
    k_wsplit<<<(256 * 256 + 255) / 256, 256, 0, stream>>>(W1, w1h, w1l, 256, 256);
    k_wsplit<<<(256 * 256 + 255) / 256, 256, 0, stream>>>(W2, w2h, w2l, 256, 256);
    k_wsplit<<<(256 * 64 + 255) / 256, 256, 0, stream>>>(W3, w3h, w3l, 256, 64);
    long nx = (long)N * 256;
    k_xsplit<<<(int)((nx + 255) / 256), 256, 0, stream>>>(x, xh, xl, nx);

    dim3 gemmBig((N + 127) / 128, 4);
    dim3 gemmSmall((N + 127) / 128, 1);
    int nodeBlocks = (N + 3) / 4;

    // layer 1 (3-term A split)
    k_gemm3<<<gemmBig, 256, 0, stream>>>(xh, xl, w1h, w1l, feat, N, 256, 256);
    k_alpha<4><<<nodeBlocks, 256, 0, stream>>>(feat, as1, ad1, als, ald, N);
    k_agg<4, true, __half><<<nodeBlocks, 256, 0, stream>>>(feat, offs, csr, als, ald, b1, act, N);
    // layer 2 (A exact f16, 2-term)
    k_gemm2<<<gemmBig, 256, 0, stream>>>(act, w2h, w2l, feat, N, 256, 256);
    k_alpha<4><<<nodeBlocks, 256, 0, stream>>>(feat, as2, ad2, als, ald, N);
    k_agg<4, true, __half><<<nodeBlocks, 256, 0, stream>>>(feat, offs, csr, als, ald, b2, act, N);
    // layer 3: 256 -> 64, single head, no ELU; fp32 straight to d_out
    k_gemm2<<<gemmSmall, 256, 0, stream>>>(act, w3h, w3l, feat, N, 256, 64);
    k_alpha<1><<<nodeBlocks, 256, 0, stream>>>(feat, as3, ad3, als, ald, N);
    k_agg<1, false, float><<<nodeBlocks, 256, 0, stream>>>(feat, offs, csr, als, ald, b3, out, N);

    // global mean pool
    k_pool2<<<G, 256, 0, stream>>>(out, batch, out + (size_t)N * 64, N);
}